// Round 6
// baseline (326.543 us; speedup 1.0000x reference)
//
#include <hip/hip_runtime.h>
#include <stdint.h>

typedef float f4 __attribute__((ext_vector_type(4)));
typedef float f32x4 __attribute__((ext_vector_type(4)));
typedef _Float16 hq4 __attribute__((ext_vector_type(4)));
typedef _Float16 half8 __attribute__((ext_vector_type(8)));

#define DF 128    // input feature dim
#define HID 64    // hidden dim
#define EPT 4     // edges per thread in scatter (782 blocks of 512)
#define SLOT 64   // slots per node (Poisson mean 16; P(deg>64) ~ 1e-19 over 100K)

// ---------- R22: one-pass gapped-CSR scatter + fused degree + W1 repack -------
// Replaces kA3+kB (two full edge passes, ~75-85us) with a single pass:
//   cd[c] = {cnt, degw_bits} (same int2 -> same cache line for both atomics,
//   and consumers get count+degree with ONE 8B load)
//   edata[c*64 + pos] = {src, w}
// Last block repacks W1 into MFMA B-fragment order (replaces kPrep).
__global__ __launch_bounds__(512) void kScatter(const int* __restrict__ row,
                                                const int* __restrict__ col,
                                                const float* __restrict__ ew,
                                                int2* __restrict__ cd,
                                                int2* __restrict__ edata,
                                                const float* __restrict__ W1,
                                                _Float16* __restrict__ W1f,
                                                int E, int nblkS) {
    int b = blockIdx.x, t = threadIdx.x;
    if (b == nblkS) {                  // W1 -> MFMA B-fragment repack (16KB)
        for (int i = t; i < 8192; i += 512) {
            int j     = i & 7;
            int lane  = (i >> 3) & 63;
            int ntile = (i >> 9) & 3;
            int kstep = i >> 11;
            int k = kstep * 32 + (lane >> 4) * 8 + j;
            int n = ntile * 16 + (lane & 15);
            W1f[i] = (_Float16)W1[k * 64 + n];
        }
        return;
    }
    int s = b * (512 * EPT), e = min(E, s + 512 * EPT);
    int  cc[EPT], pos[EPT];
    int2 rec[EPT];
    float wv[EPT];
#pragma unroll
    for (int k = 0; k < EPT; ++k) {    // coalesced loads of row/col/ew
        int i = s + t + k * 512;
        cc[k] = -1;
        if (i < e) {
            cc[k] = col[i];
            wv[k] = ew[i];
            rec[k].x = row[i];
            rec[k].y = __float_as_int(wv[k]);
        }
    }
#pragma unroll
    for (int k = 0; k < EPT; ++k) {    // EPT independent atomics in flight
        if (cc[k] >= 0) {
            unsafeAtomicAdd((float*)&cd[cc[k]].y, wv[k]);  // hw fadd, no return
            pos[k] = atomicAdd(&cd[cc[k]].x, 1);           // slot index
        }
    }
#pragma unroll
    for (int k = 0; k < EPT; ++k) {
        if (cc[k] >= 0 && pos[k] < SLOT)
            edata[((size_t)cc[k] << 6) + pos[k]] = rec[k];
    }
}

// ---------- h = fp16(dinv[n] * (x @ W1)[n]) via MFMA fp16 (R1-proven form) ----
// dinv computed inline from cd[].y (rsqrt is cheap; cd is L2-hot).
__global__ __launch_bounds__(256) void k_gemm1(const float* __restrict__ x,
                                               const _Float16* __restrict__ W1f,
                                               const int2* __restrict__ cd,
                                               _Float16* __restrict__ h, int N) {
    int wave  = (blockIdx.x * 256 + threadIdx.x) >> 6;
    int nstrip = (N + 15) >> 4;
    if (wave >= nstrip) return;
    int node0 = wave << 4;
    int l = threadIdx.x & 63;
    int quad = l >> 4;
    int m = l & 15;
    int r = node0 + m;
    if (r >= N) r = N - 1;   // clamp (harmless duplicate load)

    const half8* bfrag = (const half8*)W1f;   // 16KB, L2-resident broadcast
    f32x4 acc[4];
#pragma unroll
    for (int nt = 0; nt < 4; ++nt) acc[nt] = (f32x4)(0.f);

#pragma unroll
    for (int kstep = 0; kstep < 4; ++kstep) {
        const f4* xr = (const f4*)(x + (size_t)r * DF + kstep * 32 + quad * 8);
        f4 a0 = xr[0], a1 = xr[1];
        half8 af;
        af[0] = (_Float16)a0.x; af[1] = (_Float16)a0.y;
        af[2] = (_Float16)a0.z; af[3] = (_Float16)a0.w;
        af[4] = (_Float16)a1.x; af[5] = (_Float16)a1.y;
        af[6] = (_Float16)a1.z; af[7] = (_Float16)a1.w;
#pragma unroll
        for (int nt = 0; nt < 4; ++nt) {
            half8 bf = bfrag[(kstep * 4 + nt) * 64 + l];
            acc[nt] = __builtin_amdgcn_mfma_f32_16x16x32_f16(af, bf, acc[nt], 0, 0, 0);
        }
    }

    float dv[4];
    int nodeb = node0 + quad * 4;
#pragma unroll
    for (int reg = 0; reg < 4; ++reg)
        dv[reg] = (nodeb + reg < N)
                    ? rsqrtf(1.f + __int_as_float(cd[nodeb + reg].y)) : 0.f;
#pragma unroll
    for (int nt = 0; nt < 4; ++nt) {
#pragma unroll
        for (int reg = 0; reg < 4; ++reg) {
            int node = nodeb + reg;
            if (node < N)
                h[(unsigned)node * 64u + (unsigned)(nt * 16 + m)] =
                    (_Float16)(dv[reg] * acc[nt][reg]);
        }
    }
}

// ---------- fused layer-1 aggregate + relu + @W2 : FOUR nodes per wave ----------
// (R1-proven: 16 lanes/node, lane-local aggregation, 16 gathers in flight/wave.
//  R2's per-bucket LDS-atomic variant was 711us: TLP collapse.)
__global__ __launch_bounds__(256) void k_agg_h2(const int2* __restrict__ cd,
                                                const int2* __restrict__ edata,
                                                const _Float16* __restrict__ h,
                                                const float* __restrict__ b1,
                                                const float* __restrict__ W2,
                                                float* __restrict__ h2p, int N) {
    __shared__ int2 stage[4][68];      // 4 waves x (4 groups x 17 padded) = 2176 B
    int wv = threadIdx.x >> 6;
    int l  = threadIdx.x & 63;
    int g  = l >> 4;                   // node group within wave (0..3)
    unsigned fq = (unsigned)(l & 15);  // feature quad: features 4fq..4fq+3
    int sbase = g * 17;                // padded LDS base for this group
    int vv = blockIdx.x * 16 + wv * 4 + g;
    bool ok = vv < N;
    int v = ok ? vv : N - 1;           // clamp (harmless duplicate work)
    const hq4* hp = (const hq4*)h;     // hp[(src<<4)|fq] = 4 features (8B)

    int2 c2 = cd[v];                   // one 8B load: {cnt, degw}
    int cntv = min(c2.x, SLOT);
    float di = rsqrtf(1.f + __int_as_float(c2.y));
    int start = v << 6;

    // self-loop: every lane holds its feature quad of h'[v]
    hq4 sv4 = hp[((unsigned)v << 4) | fq];
    float a0 = (float)sv4.x, a1 = (float)sv4.y;
    float a2 = (float)sv4.z, a3 = (float)sv4.w;

    for (int base = 0; base < cntv; base += 16) {  // divergent only across groups
        int k0 = base + (int)fq;
        int2 pr;
        pr.x = 0; pr.y = 0;            // dummy: src 0, w = 0
        if (k0 < cntv) pr = edata[start + k0];
        stage[wv][sbase + (int)fq] = pr;   // wave-private row; no block barrier
#pragma unroll
        for (int k = 0; k < 16; ++k) {
            int2 em = stage[wv][sbase + k];   // 16-lane broadcast per group
            float w = __int_as_float(em.y);
            hq4 hv = hp[((unsigned)em.x << 4) | fq];
            a0 += w * (float)hv.x;
            a1 += w * (float)hv.y;
            a2 += w * (float)hv.z;
            a3 += w * (float)hv.w;
        }
    }

    a0 = di * a0; a1 = di * a1; a2 = di * a2; a3 = di * a3;
    f4 bb = ((const f4*)b1)[fq];
    f4 ww = ((const f4*)W2)[fq];
    float s = fmaxf(a0 + bb.x, 0.f) * ww.x
            + fmaxf(a1 + bb.y, 0.f) * ww.y
            + fmaxf(a2 + bb.z, 0.f) * ww.z
            + fmaxf(a3 + bb.w, 0.f) * ww.w;
    // reduce over the 16 feature-quad lanes (tree rooted at lane 16g)
    s += __shfl_down(s, 8);
    s += __shfl_down(s, 4);
    s += __shfl_down(s, 2);
    s += __shfl_down(s, 1);
    if (fq == 0 && ok) h2p[vv] = di * s;   // store dinv-scaled hidden
}

// ---------- layer-2 aggregation: 16 lanes per node; h2p pre-scaled ----------
__global__ __launch_bounds__(256) void k_out(const int2* __restrict__ cd,
                                             const int2* __restrict__ edata,
                                             const float* __restrict__ h2p,
                                             const float* __restrict__ b2,
                                             float* __restrict__ out, int N) {
    int t = blockIdx.x * 256 + threadIdx.x;
    int v = t >> 4;
    if (v >= N) return;
    int c = t & 15;
    int2 c2 = cd[v];
    int cntv = min(c2.x, SLOT);
    int start = v << 6;
    float s = 0.f;
    for (int i = c; i < cntv; i += 16) {
        int2 pr = edata[start + i];
        s += __int_as_float(pr.y) * h2p[(unsigned)pr.x];
    }
    s += __shfl_down(s, 8);
    s += __shfl_down(s, 4);
    s += __shfl_down(s, 2);
    s += __shfl_down(s, 1);
    if (c == 0) {
        float di = rsqrtf(1.f + __int_as_float(c2.y));
        out[v] = b2[0] + di * (h2p[v] + s);   // h2p[v] = di*h2[v]
    }
}

extern "C" void kernel_launch(void* const* d_in, const int* in_sizes, int n_in,
                              void* d_out, int out_size, void* d_ws, size_t ws_size,
                              hipStream_t stream) {
    const float* x  = (const float*)d_in[0];
    const int*   ei = (const int*)d_in[1];
    const float* ew = (const float*)d_in[2];
    const float* W1 = (const float*)d_in[3];
    const float* b1 = (const float*)d_in[4];
    const float* W2 = (const float*)d_in[5];
    const float* b2 = (const float*)d_in[6];
    float* out = (float*)d_out;

    const int N = in_sizes[0] / DF;       // 100000
    const int E = in_sizes[2];            // 1600000
    const int* row = ei;                  // sources
    const int* col = ei + E;              // targets

    // ---- workspace layout, ~65.2 MB ----
    int2*     edata = (int2*)d_ws;                        // N*64 int2 = 51.2 MB
    _Float16* h     = (_Float16*)(edata + (size_t)N * SLOT); // 12.8 MB
    int2*     cd    = (int2*)(h + (size_t)N * 64);        // N int2 = 800 KB
    float*    h2p   = (float*)(cd + N);                   // N floats
    _Float16* W1f   = (_Float16*)(h2p + N);               // 8192 fp16 = 16 KB

    const int B = 256;
    int nblkS  = (E + 512 * EPT - 1) / (512 * EPT);  // 782 scatter blocks
    int nstrip = (N + 15) / 16;
    int gGm  = (nstrip + 3) / 4;           // 4 waves (strips) per block
    int gAgg = (N + 15) / 16;              // 16 nodes per block (4 nodes/wave)
    int gN16 = (N * 16 + B - 1) / B;

    hipMemsetAsync(cd, 0, (size_t)N * sizeof(int2), stream);   // {cnt,degw}=0
    kScatter<<<nblkS + 1, 512, 0, stream>>>(row, col, ew, cd, edata, W1, W1f,
                                            E, nblkS);
    k_gemm1<<<gGm, B, 0, stream>>>(x, W1f, cd, h, N);
    k_agg_h2<<<gAgg, B, 0, stream>>>(cd, edata, h, b1, W2, h2p, N);
    k_out<<<gN16, B, 0, stream>>>(cd, edata, h2p, b2, out, N);
}

// Round 7
// 254.854 us; speedup vs baseline: 1.2813x; 1.2813x over previous
//
#include <hip/hip_runtime.h>
#include <stdint.h>

typedef float f4 __attribute__((ext_vector_type(4)));
typedef float f32x4 __attribute__((ext_vector_type(4)));
typedef _Float16 hq4 __attribute__((ext_vector_type(4)));
typedef _Float16 half8 __attribute__((ext_vector_type(8)));

#define DF 128    // input feature dim
#define HID 64    // hidden dim
#define EPB 4096  // edges per sort block (391 sort blocks of 512 threads, 8/thread)
#define CAP 5120  // slots per coarse bucket (avg 4096, max~4314 for seed-0 input)

// ---------- kA3: coarse bucket sort + degw (non-returning atomics) + W1 repack --
// R23: degw accumulated here via fire-and-forget global fadd (hidden in the
// sort's latency stalls; R6 showed only RETURNING atomics + scattered writes
// are poison). Block nblk repacks W1 (kPrep deleted). This breaks the
// kB -> gemm dependency so kMid can run them as one launch.
__global__ __launch_bounds__(512) void kA3(const int* __restrict__ row,
                                           const int* __restrict__ col,
                                           const float* __restrict__ ew,
                                           int* __restrict__ cur,
                                           float* __restrict__ degw,
                                           int2* __restrict__ tmp,
                                           const float* __restrict__ W1,
                                           _Float16* __restrict__ W1f,
                                           int E, int nblk) {
    int b = blockIdx.x, t = threadIdx.x;
    if (b == nblk) {                   // W1 -> MFMA B-fragment repack (16KB)
        for (int i = t; i < 8192; i += 512) {
            int j     = i & 7;
            int lane  = (i >> 3) & 63;
            int ntile = (i >> 9) & 3;
            int kstep = i >> 11;
            int k = kstep * 32 + (lane >> 4) * 8 + j;
            int n = ntile * 16 + (lane & 15);
            W1f[i] = (_Float16)W1[k * 64 + n];
        }
        return;
    }
    __shared__ int hist[512];
    __shared__ int pref[512];
    __shared__ int lbase[512];
    __shared__ int wsum[8];
    __shared__ int2 sv[EPB];   // 32 KB
    __shared__ int  sa[EPB];   // 16 KB
    hist[t] = 0;
    __syncthreads();
    int s = b * EPB, e = min(E, s + EPB);
    int cnt = e - s;
    int  mybin[8], myrank[8];
    int2 myv[8];
#pragma unroll
    for (int k = 0; k < 8; ++k) {
        int i = s + t + k * 512;
        mybin[k] = -1;
        if (i < e) {
            int c = col[i];
            float w = ew[i];
            int bin = c >> 8;
            myv[k].x = row[i] | ((c & 255) << 24);   // src 17b | fine-col<<24
            myv[k].y = __float_as_int(w);
            mybin[k] = bin;
            myrank[k] = atomicAdd(&hist[bin], 1);
            unsafeAtomicAdd(&degw[c], w);            // non-returning hw fadd
        }
    }
    __syncthreads();
    int val = hist[t];
    lbase[t] = val ? atomicAdd(&cur[t], val) + t * CAP : 0;  // absolute base
    int lane = t & 63, wid = t >> 6;
    int inc = val;
#pragma unroll
    for (int d = 1; d < 64; d <<= 1) {
        int y = __shfl_up(inc, d);
        if (lane >= d) inc += y;
    }
    if (lane == 63) wsum[wid] = inc;
    __syncthreads();
    if (t == 0) {
        int r = 0;
#pragma unroll
        for (int i = 0; i < 8; ++i) { int xx = wsum[i]; wsum[i] = r; r += xx; }
    }
    __syncthreads();
    pref[t] = inc - val + wsum[wid];   // exclusive prefix within block
    __syncthreads();
#pragma unroll
    for (int k = 0; k < 8; ++k) {
        if (mybin[k] >= 0) {
            int pos = pref[mybin[k]] + myrank[k];
            sv[pos] = myv[k];
            sa[pos] = lbase[mybin[k]] + myrank[k];
        }
    }
    __syncthreads();
    for (int i = t; i < cnt; i += 512) tmp[sa[i]] = sv[i];
}

// ---------- kMid: fine sort (blocks < nbin)  ||  h = fp16(dinv * x@W1) --------
// R23: both depend only on kA3 -> one launch; gemm's MFMA/VMEM stream fills
// the sort blocks' stall slots (R5-proven mechanism, without R5's g-detour).
// kB branch simplified: no degl float atomics (degw came from kA3).
__global__ __launch_bounds__(512) void kMid(const int2* __restrict__ tmp,
                                            const int* __restrict__ cur,
                                            int2* __restrict__ edata,
                                            int2* __restrict__ offse,
                                            const float* __restrict__ x,
                                            const _Float16* __restrict__ W1f,
                                            const float* __restrict__ degw,
                                            _Float16* __restrict__ h,
                                            int nbin, int nstrip, int N) {
    __shared__ int   hist[256];
    __shared__ int   fill[256];
    __shared__ int   wsum[8];
    __shared__ int2  se[CAP];   // 40 KB staged entries (LDS 43KB -> 3 blocks/CU)
    int t = threadIdx.x;

    if ((int)blockIdx.x < nbin) {
        // ================= fine-sort branch =================
        int bin = blockIdx.x;
        int s = bin * CAP;
        int cnt = min(cur[bin], CAP);
        if (t < 256) hist[t] = 0;
        __syncthreads();
        for (int i = t; i < cnt; i += 512) {
            int2 pr = tmp[s + i];
            se[i] = pr;
            atomicAdd(&hist[((unsigned)pr.x) >> 24], 1);
        }
        __syncthreads();
        int val = (t < 256) ? hist[t] : 0;
        int lane = t & 63, wid = t >> 6;
        int inc = val;
#pragma unroll
        for (int d = 1; d < 64; d <<= 1) {
            int y = __shfl_up(inc, d);
            if (lane >= d) inc += y;
        }
        if (lane == 63) wsum[wid] = inc;
        __syncthreads();
        if (t == 0) {
            int r = 0;
#pragma unroll
            for (int i = 0; i < 8; ++i) { int xx = wsum[i]; wsum[i] = r; r += xx; }
        }
        __syncthreads();
        int pfx = inc - val + wsum[wid];   // exclusive prefix (valid t<256)
        if (t < 256) {
            fill[t] = pfx;
            int c = bin * 256 + t;
            if (c < N) {
                int2 oe;
                oe.x = s + pfx;
                oe.y = s + pfx + val;
                offse[c] = oe;
            }
        }
        __syncthreads();
        for (int i = t; i < cnt; i += 512) {
            int2 pr = se[i];
            int lo = ((unsigned)pr.x) >> 24;
            int pos = atomicAdd(&fill[lo], 1);
            int2 o;
            o.x = pr.x & 0x00FFFFFF;
            o.y = pr.y;
            edata[s + pos] = o;    // scattered within 40KB window -> L2-absorbed
        }
    } else {
        // ================= gemm branch: h = fp16(rsqrt(1+degw) * x@W1) ======
        int wave = ((int)blockIdx.x - nbin) * 8 + (t >> 6);
        if (wave >= nstrip) return;
        int node0 = wave << 4;
        int l = t & 63;
        int quad = l >> 4;
        int m = l & 15;
        int r = node0 + m;
        if (r >= N) r = N - 1;   // clamp (harmless duplicate load)

        const half8* bfrag = (const half8*)W1f;   // 16KB, L2-hot broadcast
        f32x4 acc[4];
#pragma unroll
        for (int nt = 0; nt < 4; ++nt) acc[nt] = (f32x4)(0.f);
#pragma unroll
        for (int kstep = 0; kstep < 4; ++kstep) {
            const f4* xr = (const f4*)(x + (size_t)r * DF + kstep * 32 + quad * 8);
            f4 a0 = xr[0], a1 = xr[1];
            half8 af;
            af[0] = (_Float16)a0.x; af[1] = (_Float16)a0.y;
            af[2] = (_Float16)a0.z; af[3] = (_Float16)a0.w;
            af[4] = (_Float16)a1.x; af[5] = (_Float16)a1.y;
            af[6] = (_Float16)a1.z; af[7] = (_Float16)a1.w;
#pragma unroll
            for (int nt = 0; nt < 4; ++nt) {
                half8 bf = bfrag[(kstep * 4 + nt) * 64 + l];
                acc[nt] = __builtin_amdgcn_mfma_f32_16x16x32_f16(af, bf, acc[nt], 0, 0, 0);
            }
        }
        float dv[4];
        int nodeb = node0 + quad * 4;
#pragma unroll
        for (int reg = 0; reg < 4; ++reg)
            dv[reg] = (nodeb + reg < N) ? rsqrtf(1.f + degw[nodeb + reg]) : 0.f;
#pragma unroll
        for (int nt = 0; nt < 4; ++nt) {
#pragma unroll
            for (int reg = 0; reg < 4; ++reg) {
                int node = nodeb + reg;
                if (node < N)
                    h[(unsigned)node * 64u + (unsigned)(nt * 16 + m)] =
                        (_Float16)(dv[reg] * acc[nt][reg]);
            }
        }
    }
}

// ---------- fused layer-1 aggregate + relu + @W2 : FOUR nodes per wave ----------
// (R1-proven: 16 lanes/node, lane-local aggregation, 16 gathers in flight/wave.)
__global__ __launch_bounds__(256) void k_agg_h2(const int2* __restrict__ offse,
                                                const int2* __restrict__ edata,
                                                const float* __restrict__ degw,
                                                const _Float16* __restrict__ h,
                                                const float* __restrict__ b1,
                                                const float* __restrict__ W2,
                                                float* __restrict__ h2p, int N) {
    __shared__ int2 stage[4][68];      // 4 waves x (4 groups x 17 padded) = 2176 B
    int wv = threadIdx.x >> 6;
    int l  = threadIdx.x & 63;
    int g  = l >> 4;                   // node group within wave (0..3)
    unsigned fq = (unsigned)(l & 15);  // feature quad: features 4fq..4fq+3
    int sbase = g * 17;                // padded LDS base for this group
    int vv = blockIdx.x * 16 + wv * 4 + g;
    bool ok = vv < N;
    int v = ok ? vv : N - 1;           // clamp (harmless duplicate work)
    const hq4* hp = (const hq4*)h;     // hp[(src<<4)|fq] = 4 features (8B)

    float di = rsqrtf(1.f + degw[v]);  // L2-hot 400KB, cheap
    int2 oe = offse[v];

    // self-loop: every lane holds its feature quad of h'[v]
    hq4 sv4 = hp[((unsigned)v << 4) | fq];
    float a0 = (float)sv4.x, a1 = (float)sv4.y;
    float a2 = (float)sv4.z, a3 = (float)sv4.w;

    int deg = oe.y - oe.x;
    for (int base = 0; base < deg; base += 16) {   // divergent only across groups
        int idx = oe.x + base + (int)fq;
        int2 pr;
        pr.x = 0; pr.y = 0;            // dummy: src 0, w = 0
        if (idx < oe.y) pr = edata[idx];
        stage[wv][sbase + (int)fq] = pr;   // wave-private row; no block barrier
#pragma unroll
        for (int k = 0; k < 16; ++k) {
            int2 em = stage[wv][sbase + k];   // 16-lane broadcast per group
            float w = __int_as_float(em.y);
            hq4 hv = hp[((unsigned)em.x << 4) | fq];
            a0 += w * (float)hv.x;
            a1 += w * (float)hv.y;
            a2 += w * (float)hv.z;
            a3 += w * (float)hv.w;
        }
    }

    a0 = di * a0; a1 = di * a1; a2 = di * a2; a3 = di * a3;
    f4 bb = ((const f4*)b1)[fq];
    f4 ww = ((const f4*)W2)[fq];
    float s = fmaxf(a0 + bb.x, 0.f) * ww.x
            + fmaxf(a1 + bb.y, 0.f) * ww.y
            + fmaxf(a2 + bb.z, 0.f) * ww.z
            + fmaxf(a3 + bb.w, 0.f) * ww.w;
    // reduce over the 16 feature-quad lanes (tree rooted at lane 16g)
    s += __shfl_down(s, 8);
    s += __shfl_down(s, 4);
    s += __shfl_down(s, 2);
    s += __shfl_down(s, 1);
    if (fq == 0 && ok) h2p[vv] = di * s;   // store dinv-scaled hidden
}

// ---------- layer-2 aggregation: 16 lanes per node; h2p pre-scaled ----------
__global__ __launch_bounds__(256) void k_out(const int2* __restrict__ offse,
                                             const int2* __restrict__ edata,
                                             const float* __restrict__ degw,
                                             const float* __restrict__ h2p,
                                             const float* __restrict__ b2,
                                             float* __restrict__ out, int N) {
    int t = blockIdx.x * 256 + threadIdx.x;
    int v = t >> 4;
    if (v >= N) return;
    int c = t & 15;
    int2 oe = offse[v];
    float s = 0.f;
    for (int i = oe.x + c; i < oe.y; i += 16) {
        int2 pr = edata[i];
        s += __int_as_float(pr.y) * h2p[(unsigned)pr.x];
    }
    s += __shfl_down(s, 8);
    s += __shfl_down(s, 4);
    s += __shfl_down(s, 2);
    s += __shfl_down(s, 1);
    if (c == 0) {
        float di = rsqrtf(1.f + degw[v]);
        out[v] = b2[0] + di * (h2p[v] + s);   // h2p[v] = di*h2[v]
    }
}

extern "C" void kernel_launch(void* const* d_in, const int* in_sizes, int n_in,
                              void* d_out, int out_size, void* d_ws, size_t ws_size,
                              hipStream_t stream) {
    const float* x  = (const float*)d_in[0];
    const int*   ei = (const int*)d_in[1];
    const float* ew = (const float*)d_in[2];
    const float* W1 = (const float*)d_in[3];
    const float* b1 = (const float*)d_in[4];
    const float* W2 = (const float*)d_in[5];
    const float* b2 = (const float*)d_in[6];
    float* out = (float*)d_out;

    const int N = in_sizes[0] / DF;       // 100000
    const int E = in_sizes[2];            // 1600000
    const int* row = ei;                  // sources
    const int* col = ei + E;              // targets

    const int nbin = (N + 255) / 256;     // 391 coarse buckets
    const int nblk = (E + EPB - 1) / EPB; // 391 sort blocks

    // ---- workspace layout, ~46.5 MB ----
    size_t    gsz   = (size_t)nbin * CAP;                 // gapped entry count
    int2*     edata = (int2*)d_ws;                        // 16.0 MB
    int2*     tmp   = edata + gsz;                        // 16.0 MB
    _Float16* h     = (_Float16*)(tmp + gsz);             // N*64 fp16 = 12.8 MB
    int       nbinPad = (nbin + 3) & ~3;
    int*      cur   = (int*)(h + (size_t)N * 64);         // nbinPad ints
    float*    degw  = (float*)(cur + nbinPad);            // N floats (contig w/ cur)
    float*    h2p   = degw + N;                           // N floats
    int2*     offse = (int2*)(h2p + N);                   // N int2
    _Float16* W1f   = (_Float16*)(offse + N);             // 8192 fp16 = 16 KB

    const int B = 256;
    int nstrip = (N + 15) / 16;            // 6250 GEMM strips (16 nodes/wave)
    int gemmBlocks = (nstrip + 7) / 8;     // 8 waves per 512-thread block
    int gAgg = (N + 15) / 16;              // 16 nodes per block (4 nodes/wave)
    int gN16 = (N * 16 + B - 1) / B;

    hipMemsetAsync(cur, 0, (size_t)(nbinPad + N) * sizeof(int), stream);
    kA3<<<nblk + 1, 512, 0, stream>>>(row, col, ew, cur, degw, tmp, W1, W1f,
                                      E, nblk);
    kMid<<<nbin + gemmBlocks, 512, 0, stream>>>(tmp, cur, edata, offse,
                                                x, W1f, degw, h,
                                                nbin, nstrip, N);
    k_agg_h2<<<gAgg, B, 0, stream>>>(offse, edata, degw, h, b1, W2, h2p, N);
    k_out<<<gN16, B, 0, stream>>>(offse, edata, degw, h2p, b2, out, N);
}

// Round 8
// 197.047 us; speedup vs baseline: 1.6572x; 1.2934x over previous
//
#include <hip/hip_runtime.h>
#include <stdint.h>

typedef float f4 __attribute__((ext_vector_type(4)));
typedef float f32x4 __attribute__((ext_vector_type(4)));
typedef _Float16 hq4 __attribute__((ext_vector_type(4)));
typedef _Float16 half8 __attribute__((ext_vector_type(8)));

#define DF 128    // input feature dim
#define HID 64    // hidden dim
#define EPB 4096  // edges per sort block (391 sort blocks of 512 threads, 8/thread)
#define CAP 5120  // slots per coarse bucket (avg 4096, max~4314 for seed-0 input)

// ---------- kFusedA: coarse bucket sort (blocks<nblk) || h = fp16(x@W1) -------
// R24: R5-proven fusion (gemm hides in sort's stall slots, kFused==sort-alone
// at 42us) WITHOUT R5's fp32-g detour: h is stored UNSCALED fp16; the src-side
// dinv scale moves to the aggregator as a broadcast 4B load (L2-hot, hides
// under the 128B h-row gather). No per-edge global atomics (R6/R7 lesson).
__global__ __launch_bounds__(512) void kFusedA(const int* __restrict__ row,
                                               const int* __restrict__ col,
                                               const float* __restrict__ ew,
                                               int* __restrict__ cur,
                                               int2* __restrict__ tmp,
                                               const float* __restrict__ x,
                                               const float* __restrict__ W1,
                                               _Float16* __restrict__ h,
                                               int E, int nblk, int nstrip, int N) {
    __shared__ __align__(16) char smem[55360];   // union: sort 54.1KB / gemm 16KB
    int t = threadIdx.x;

    if ((int)blockIdx.x < nblk) {
        // ================= sort branch (R3/R5-proven dataflow) ==============
        int*  hist  = (int*)smem;                    // 512
        int*  pref  = hist + 512;                    // 512
        int*  lbase = pref + 512;                    // 512
        int*  wsum  = lbase + 512;                   // 8
        int2* sv    = (int2*)(smem + 6208);          // EPB int2 = 32 KB
        int*  sa    = (int*)(smem + 6208 + 32768);   // EPB int  = 16 KB
        int b = blockIdx.x;
        hist[t] = 0;
        __syncthreads();
        int s = b * EPB, e = min(E, s + EPB);
        int cnt = e - s;
        int  mybin[8], myrank[8];
        int2 myv[8];
#pragma unroll
        for (int k = 0; k < 8; ++k) {
            int i = s + t + k * 512;
            mybin[k] = -1;
            if (i < e) {
                int c = col[i];
                int bin = c >> 8;
                myv[k].x = row[i] | ((c & 255) << 24);   // src 17b | fine-col<<24
                myv[k].y = __float_as_int(ew[i]);
                mybin[k] = bin;
                myrank[k] = atomicAdd(&hist[bin], 1);
            }
        }
        __syncthreads();
        int val = hist[t];
        lbase[t] = val ? atomicAdd(&cur[t], val) + t * CAP : 0;  // absolute base
        int lane = t & 63, wid = t >> 6;
        int inc = val;
#pragma unroll
        for (int d = 1; d < 64; d <<= 1) {
            int y = __shfl_up(inc, d);
            if (lane >= d) inc += y;
        }
        if (lane == 63) wsum[wid] = inc;
        __syncthreads();
        if (t == 0) {
            int r = 0;
#pragma unroll
            for (int i = 0; i < 8; ++i) { int xx = wsum[i]; wsum[i] = r; r += xx; }
        }
        __syncthreads();
        pref[t] = inc - val + wsum[wid];   // exclusive prefix within block
        __syncthreads();
#pragma unroll
        for (int k = 0; k < 8; ++k) {
            if (mybin[k] >= 0) {
                int pos = pref[mybin[k]] + myrank[k];
                sv[pos] = myv[k];
                sa[pos] = lbase[mybin[k]] + myrank[k];
            }
        }
        __syncthreads();
        for (int i = t; i < cnt; i += 512) tmp[sa[i]] = sv[i];
    } else {
        // ================= gemm branch: h = fp16(x @ W1), UNSCALED ==========
        _Float16* W1f = (_Float16*)smem;             // 16 KB LDS B-fragments
        for (int i = t; i < 8192; i += 512) {
            int j     = i & 7;
            int lane  = (i >> 3) & 63;
            int ntile = (i >> 9) & 3;
            int kstep = i >> 11;
            int k = kstep * 32 + (lane >> 4) * 8 + j;
            int n = ntile * 16 + (lane & 15);
            W1f[i] = (_Float16)W1[k * 64 + n];       // W1 32KB -> L2-hot
        }
        __syncthreads();
        int wave = ((int)blockIdx.x - nblk) * 8 + (t >> 6);
        if (wave >= nstrip) return;
        int node0 = wave << 4;
        int l = t & 63;
        int quad = l >> 4;
        int m = l & 15;
        int r = node0 + m;
        if (r >= N) r = N - 1;   // clamp (harmless duplicate load)

        const half8* bfrag = (const half8*)W1f;
        f32x4 acc[4];
#pragma unroll
        for (int nt = 0; nt < 4; ++nt) acc[nt] = (f32x4)(0.f);
#pragma unroll
        for (int kstep = 0; kstep < 4; ++kstep) {
            const f4* xr = (const f4*)(x + (size_t)r * DF + kstep * 32 + quad * 8);
            f4 a0 = xr[0], a1 = xr[1];
            half8 af;
            af[0] = (_Float16)a0.x; af[1] = (_Float16)a0.y;
            af[2] = (_Float16)a0.z; af[3] = (_Float16)a0.w;
            af[4] = (_Float16)a1.x; af[5] = (_Float16)a1.y;
            af[6] = (_Float16)a1.z; af[7] = (_Float16)a1.w;
#pragma unroll
            for (int nt = 0; nt < 4; ++nt) {
                half8 bf = bfrag[(kstep * 4 + nt) * 64 + l];
                acc[nt] = __builtin_amdgcn_mfma_f32_16x16x32_f16(af, bf, acc[nt], 0, 0, 0);
            }
        }
        int nodeb = node0 + quad * 4;
#pragma unroll
        for (int nt = 0; nt < 4; ++nt) {
#pragma unroll
            for (int reg = 0; reg < 4; ++reg) {
                int node = nodeb + reg;
                if (node < N)
                    h[(unsigned)node * 64u + (unsigned)(nt * 16 + m)] =
                        (_Float16)acc[nt][reg];
            }
        }
    }
}

// ---------- kB: fine sort in LDS + degl/dinv + scattered edata (R3-proven) ----
__global__ __launch_bounds__(512) void kB(const int2* __restrict__ tmp,
                                          const int* __restrict__ cur,
                                          int2* __restrict__ edata,
                                          int2* __restrict__ offse,
                                          float* __restrict__ dinv,
                                          int N) {
    __shared__ int   hist[256];
    __shared__ float degl[256];
    __shared__ int   fill[256];
    __shared__ int   wsum[8];
    __shared__ int2  se[CAP];   // 40 KB staged entries
    int bin = blockIdx.x, t = threadIdx.x;
    int s = bin * CAP;
    int cnt = min(cur[bin], CAP);

    if (t < 256) { hist[t] = 0; degl[t] = 0.f; }
    __syncthreads();
    for (int i = t; i < cnt; i += 512) {
        int2 pr = tmp[s + i];
        se[i] = pr;
        int lo = ((unsigned)pr.x) >> 24;
        atomicAdd(&hist[lo], 1);
        atomicAdd(&degl[lo], __int_as_float(pr.y));
    }
    __syncthreads();
    int val = (t < 256) ? hist[t] : 0;
    int lane = t & 63, wid = t >> 6;
    int inc = val;
#pragma unroll
    for (int d = 1; d < 64; d <<= 1) {
        int y = __shfl_up(inc, d);
        if (lane >= d) inc += y;
    }
    if (lane == 63) wsum[wid] = inc;
    __syncthreads();
    if (t == 0) {
        int r = 0;
#pragma unroll
        for (int i = 0; i < 8; ++i) { int x = wsum[i]; wsum[i] = r; r += x; }
    }
    __syncthreads();
    int pfx = inc - val + wsum[wid];   // exclusive prefix (valid for t<256)
    if (t < 256) {
        fill[t] = pfx;
        int c = bin * 256 + t;
        if (c < N) {
            int2 oe;
            oe.x = s + pfx;
            oe.y = s + pfx + val;
            offse[c] = oe;
            dinv[c] = rsqrtf(1.0f + degl[t]);   // deg >= 1 (self-loop)
        }
    }
    __syncthreads();
    for (int i = t; i < cnt; i += 512) {
        int2 pr = se[i];
        int lo = ((unsigned)pr.x) >> 24;
        int pos = atomicAdd(&fill[lo], 1);
        int2 o;
        o.x = pr.x & 0x00FFFFFF;
        o.y = pr.y;
        edata[s + pos] = o;    // scattered within 40KB window -> L2-absorbed
    }
}

// ---------- fused layer-1 aggregate + relu + @W2 : FOUR nodes per wave ----------
// R24: h is UNSCALED; per-edge scale = w * dinv[src] via broadcast 4B load
// (all 16 lanes same address; hides under the 128B h-row gather).
__global__ __launch_bounds__(256) void k_agg_h2(const int2* __restrict__ offse,
                                                const int2* __restrict__ edata,
                                                const float* __restrict__ dinv,
                                                const _Float16* __restrict__ h,
                                                const float* __restrict__ b1,
                                                const float* __restrict__ W2,
                                                float* __restrict__ h2p, int N) {
    __shared__ int2 stage[4][68];      // 4 waves x (4 groups x 17 padded) = 2176 B
    int wv = threadIdx.x >> 6;
    int l  = threadIdx.x & 63;
    int g  = l >> 4;                   // node group within wave (0..3)
    unsigned fq = (unsigned)(l & 15);  // feature quad: features 4fq..4fq+3
    int sbase = g * 17;                // padded LDS base for this group
    int vv = blockIdx.x * 16 + wv * 4 + g;
    bool ok = vv < N;
    int v = ok ? vv : N - 1;           // clamp (harmless duplicate work)
    const hq4* hp = (const hq4*)h;     // hp[(src<<4)|fq] = 4 features (8B)

    float di = dinv[v];
    int2 oe = offse[v];

    // self-loop (norm di*1*di): src-side di applied here, col-side at the end
    hq4 sv4 = hp[((unsigned)v << 4) | fq];
    float a0 = di * (float)sv4.x, a1 = di * (float)sv4.y;
    float a2 = di * (float)sv4.z, a3 = di * (float)sv4.w;

    int deg = oe.y - oe.x;
    for (int base = 0; base < deg; base += 16) {   // divergent only across groups
        int idx = oe.x + base + (int)fq;
        int2 pr;
        pr.x = 0; pr.y = 0;            // dummy: src 0, w = 0
        if (idx < oe.y) pr = edata[idx];
        stage[wv][sbase + (int)fq] = pr;   // wave-private row; no block barrier
#pragma unroll
        for (int k = 0; k < 16; ++k) {
            int2 em = stage[wv][sbase + k];   // 16-lane broadcast per group
            float ws = __int_as_float(em.y) * dinv[em.x];  // broadcast 4B load
            hq4 hv = hp[((unsigned)em.x << 4) | fq];
            a0 += ws * (float)hv.x;
            a1 += ws * (float)hv.y;
            a2 += ws * (float)hv.z;
            a3 += ws * (float)hv.w;
        }
    }

    a0 = di * a0; a1 = di * a1; a2 = di * a2; a3 = di * a3;
    f4 bb = ((const f4*)b1)[fq];
    f4 ww = ((const f4*)W2)[fq];
    float s = fmaxf(a0 + bb.x, 0.f) * ww.x
            + fmaxf(a1 + bb.y, 0.f) * ww.y
            + fmaxf(a2 + bb.z, 0.f) * ww.z
            + fmaxf(a3 + bb.w, 0.f) * ww.w;
    // reduce over the 16 feature-quad lanes (tree rooted at lane 16g)
    s += __shfl_down(s, 8);
    s += __shfl_down(s, 4);
    s += __shfl_down(s, 2);
    s += __shfl_down(s, 1);
    if (fq == 0 && ok) h2p[vv] = di * s;   // store dinv-scaled hidden
}

// ---------- layer-2 aggregation: 16 lanes per node; h2p pre-scaled ----------
__global__ __launch_bounds__(256) void k_out(const int2* __restrict__ offse,
                                             const int2* __restrict__ edata,
                                             const float* __restrict__ dinv,
                                             const float* __restrict__ h2p,
                                             const float* __restrict__ b2,
                                             float* __restrict__ out, int N) {
    int t = blockIdx.x * 256 + threadIdx.x;
    int v = t >> 4;
    if (v >= N) return;
    int c = t & 15;
    int2 oe = offse[v];
    float s = 0.f;
    for (int i = oe.x + c; i < oe.y; i += 16) {
        int2 pr = edata[i];
        s += __int_as_float(pr.y) * h2p[(unsigned)pr.x];
    }
    s += __shfl_down(s, 8);
    s += __shfl_down(s, 4);
    s += __shfl_down(s, 2);
    s += __shfl_down(s, 1);
    if (c == 0) {
        float di = dinv[v];
        out[v] = b2[0] + di * (h2p[v] + s);   // h2p[v] = di*h2[v]
    }
}

extern "C" void kernel_launch(void* const* d_in, const int* in_sizes, int n_in,
                              void* d_out, int out_size, void* d_ws, size_t ws_size,
                              hipStream_t stream) {
    const float* x  = (const float*)d_in[0];
    const int*   ei = (const int*)d_in[1];
    const float* ew = (const float*)d_in[2];
    const float* W1 = (const float*)d_in[3];
    const float* b1 = (const float*)d_in[4];
    const float* W2 = (const float*)d_in[5];
    const float* b2 = (const float*)d_in[6];
    float* out = (float*)d_out;

    const int N = in_sizes[0] / DF;       // 100000
    const int E = in_sizes[2];            // 1600000
    const int* row = ei;                  // sources
    const int* col = ei + E;              // targets

    const int nbin = (N + 255) / 256;     // 391 coarse buckets
    const int nblk = (E + EPB - 1) / EPB; // 391 sort blocks

    // ---- workspace layout, ~46.5 MB ----
    size_t    gsz   = (size_t)nbin * CAP;                 // gapped entry count
    int2*     edata = (int2*)d_ws;                        // 16.0 MB
    int2*     tmp   = edata + gsz;                        // 16.0 MB
    _Float16* h     = (_Float16*)(tmp + gsz);             // N*64 fp16 = 12.8 MB
    int       nbinPad = (nbin + 3) & ~3;
    int*      cur   = (int*)(h + (size_t)N * 64);         // nbinPad ints
    float*    dinv  = (float*)(cur + nbinPad);            // N floats
    float*    h2p   = dinv + N;                           // N floats
    int2*     offse = (int2*)(h2p + N);                   // N int2

    const int B = 256;
    int nstrip = (N + 15) / 16;            // 6250 GEMM strips (16 nodes/wave)
    int gemmBlocks = (nstrip + 7) / 8;     // 8 waves per 512-thread block
    int gAgg = (N + 15) / 16;              // 16 nodes per block (4 nodes/wave)
    int gN16 = (N * 16 + B - 1) / B;

    hipMemsetAsync(cur, 0, (size_t)nbinPad * sizeof(int), stream);
    kFusedA<<<nblk + gemmBlocks, 512, 0, stream>>>(row, col, ew, cur, tmp,
                                                   x, W1, h, E, nblk, nstrip, N);
    kB<<<nbin, 512, 0, stream>>>(tmp, cur, edata, offse, dinv, N);
    k_agg_h2<<<gAgg, B, 0, stream>>>(offse, edata, dinv, h, b1, W2, h2p, N);
    k_out<<<gN16, B, 0, stream>>>(offse, edata, dinv, h2p, b2, out, N);
}

// Round 9
// 193.221 us; speedup vs baseline: 1.6900x; 1.0198x over previous
//
#include <hip/hip_runtime.h>
#include <stdint.h>

typedef float f4 __attribute__((ext_vector_type(4)));
typedef float f32x4 __attribute__((ext_vector_type(4)));
typedef _Float16 hq4 __attribute__((ext_vector_type(4)));
typedef _Float16 half8 __attribute__((ext_vector_type(8)));

#define DF 128    // input feature dim
#define HID 64    // hidden dim
#define EPB 4096  // edges per sort block (391 sort blocks of 512 threads, 8/thread)
#define CAP 5120  // slots per coarse bucket (avg 4096, max~4314 for seed-0 input)

// ---------- kFusedA: coarse bucket sort (blocks<nblk) || h = fp16(x@W1) -------
// R24/R25: R5-proven fusion (gemm hides in sort's stall slots) with UNSCALED
// fp16 h; src-side dinv applied in the aggregator ONCE PER EDGE at staging
// (R8 lesson: per-consumer-lane dinv loads doubled VMEM issue, +27% agg time).
__global__ __launch_bounds__(512) void kFusedA(const int* __restrict__ row,
                                               const int* __restrict__ col,
                                               const float* __restrict__ ew,
                                               int* __restrict__ cur,
                                               int2* __restrict__ tmp,
                                               const float* __restrict__ x,
                                               const float* __restrict__ W1,
                                               _Float16* __restrict__ h,
                                               int E, int nblk, int nstrip, int N) {
    __shared__ __align__(16) char smem[55360];   // union: sort 54.1KB / gemm 16KB
    int t = threadIdx.x;

    if ((int)blockIdx.x < nblk) {
        // ================= sort branch (R3/R5-proven dataflow) ==============
        int*  hist  = (int*)smem;                    // 512
        int*  pref  = hist + 512;                    // 512
        int*  lbase = pref + 512;                    // 512
        int*  wsum  = lbase + 512;                   // 8
        int2* sv    = (int2*)(smem + 6208);          // EPB int2 = 32 KB
        int*  sa    = (int*)(smem + 6208 + 32768);   // EPB int  = 16 KB
        int b = blockIdx.x;
        hist[t] = 0;
        __syncthreads();
        int s = b * EPB, e = min(E, s + EPB);
        int cnt = e - s;
        int  mybin[8], myrank[8];
        int2 myv[8];
#pragma unroll
        for (int k = 0; k < 8; ++k) {
            int i = s + t + k * 512;
            mybin[k] = -1;
            if (i < e) {
                int c = col[i];
                int bin = c >> 8;
                myv[k].x = row[i] | ((c & 255) << 24);   // src 17b | fine-col<<24
                myv[k].y = __float_as_int(ew[i]);
                mybin[k] = bin;
                myrank[k] = atomicAdd(&hist[bin], 1);
            }
        }
        __syncthreads();
        int val = hist[t];
        lbase[t] = val ? atomicAdd(&cur[t], val) + t * CAP : 0;  // absolute base
        int lane = t & 63, wid = t >> 6;
        int inc = val;
#pragma unroll
        for (int d = 1; d < 64; d <<= 1) {
            int y = __shfl_up(inc, d);
            if (lane >= d) inc += y;
        }
        if (lane == 63) wsum[wid] = inc;
        __syncthreads();
        if (t == 0) {
            int r = 0;
#pragma unroll
            for (int i = 0; i < 8; ++i) { int xx = wsum[i]; wsum[i] = r; r += xx; }
        }
        __syncthreads();
        pref[t] = inc - val + wsum[wid];   // exclusive prefix within block
        __syncthreads();
#pragma unroll
        for (int k = 0; k < 8; ++k) {
            if (mybin[k] >= 0) {
                int pos = pref[mybin[k]] + myrank[k];
                sv[pos] = myv[k];
                sa[pos] = lbase[mybin[k]] + myrank[k];
            }
        }
        __syncthreads();
        for (int i = t; i < cnt; i += 512) tmp[sa[i]] = sv[i];
    } else {
        // ================= gemm branch: h = fp16(x @ W1), UNSCALED ==========
        _Float16* W1f = (_Float16*)smem;             // 16 KB LDS B-fragments
        for (int i = t; i < 8192; i += 512) {
            int j     = i & 7;
            int lane  = (i >> 3) & 63;
            int ntile = (i >> 9) & 3;
            int kstep = i >> 11;
            int k = kstep * 32 + (lane >> 4) * 8 + j;
            int n = ntile * 16 + (lane & 15);
            W1f[i] = (_Float16)W1[k * 64 + n];       // W1 32KB -> L2-hot
        }
        __syncthreads();
        int wave = ((int)blockIdx.x - nblk) * 8 + (t >> 6);
        if (wave >= nstrip) return;
        int node0 = wave << 4;
        int l = t & 63;
        int quad = l >> 4;
        int m = l & 15;
        int r = node0 + m;
        if (r >= N) r = N - 1;   // clamp (harmless duplicate load)

        const half8* bfrag = (const half8*)W1f;
        f32x4 acc[4];
#pragma unroll
        for (int nt = 0; nt < 4; ++nt) acc[nt] = (f32x4)(0.f);
#pragma unroll
        for (int kstep = 0; kstep < 4; ++kstep) {
            const f4* xr = (const f4*)(x + (size_t)r * DF + kstep * 32 + quad * 8);
            f4 a0 = xr[0], a1 = xr[1];
            half8 af;
            af[0] = (_Float16)a0.x; af[1] = (_Float16)a0.y;
            af[2] = (_Float16)a0.z; af[3] = (_Float16)a0.w;
            af[4] = (_Float16)a1.x; af[5] = (_Float16)a1.y;
            af[6] = (_Float16)a1.z; af[7] = (_Float16)a1.w;
#pragma unroll
            for (int nt = 0; nt < 4; ++nt) {
                half8 bf = bfrag[(kstep * 4 + nt) * 64 + l];
                acc[nt] = __builtin_amdgcn_mfma_f32_16x16x32_f16(af, bf, acc[nt], 0, 0, 0);
            }
        }
        int nodeb = node0 + quad * 4;
#pragma unroll
        for (int nt = 0; nt < 4; ++nt) {
#pragma unroll
            for (int reg = 0; reg < 4; ++reg) {
                int node = nodeb + reg;
                if (node < N)
                    h[(unsigned)node * 64u + (unsigned)(nt * 16 + m)] =
                        (_Float16)acc[nt][reg];
            }
        }
    }
}

// ---------- kB: fine sort in LDS + degl/dinv + scattered edata (R3-proven) ----
__global__ __launch_bounds__(512) void kB(const int2* __restrict__ tmp,
                                          const int* __restrict__ cur,
                                          int2* __restrict__ edata,
                                          int2* __restrict__ offse,
                                          float* __restrict__ dinv,
                                          int N) {
    __shared__ int   hist[256];
    __shared__ float degl[256];
    __shared__ int   fill[256];
    __shared__ int   wsum[8];
    __shared__ int2  se[CAP];   // 40 KB staged entries
    int bin = blockIdx.x, t = threadIdx.x;
    int s = bin * CAP;
    int cnt = min(cur[bin], CAP);

    if (t < 256) { hist[t] = 0; degl[t] = 0.f; }
    __syncthreads();
    for (int i = t; i < cnt; i += 512) {
        int2 pr = tmp[s + i];
        se[i] = pr;
        int lo = ((unsigned)pr.x) >> 24;
        atomicAdd(&hist[lo], 1);
        atomicAdd(&degl[lo], __int_as_float(pr.y));
    }
    __syncthreads();
    int val = (t < 256) ? hist[t] : 0;
    int lane = t & 63, wid = t >> 6;
    int inc = val;
#pragma unroll
    for (int d = 1; d < 64; d <<= 1) {
        int y = __shfl_up(inc, d);
        if (lane >= d) inc += y;
    }
    if (lane == 63) wsum[wid] = inc;
    __syncthreads();
    if (t == 0) {
        int r = 0;
#pragma unroll
        for (int i = 0; i < 8; ++i) { int x = wsum[i]; wsum[i] = r; r += x; }
    }
    __syncthreads();
    int pfx = inc - val + wsum[wid];   // exclusive prefix (valid for t<256)
    if (t < 256) {
        fill[t] = pfx;
        int c = bin * 256 + t;
        if (c < N) {
            int2 oe;
            oe.x = s + pfx;
            oe.y = s + pfx + val;
            offse[c] = oe;
            dinv[c] = rsqrtf(1.0f + degl[t]);   // deg >= 1 (self-loop)
        }
    }
    __syncthreads();
    for (int i = t; i < cnt; i += 512) {
        int2 pr = se[i];
        int lo = ((unsigned)pr.x) >> 24;
        int pos = atomicAdd(&fill[lo], 1);
        int2 o;
        o.x = pr.x & 0x00FFFFFF;
        o.y = pr.y;
        edata[s + pos] = o;    // scattered within 40KB window -> L2-absorbed
    }
}

// ---------- fused layer-1 aggregate + relu + @W2 : FOUR nodes per wave ----------
// R25: staging lane pre-multiplies w *= dinv[src] (ONE dinv load per edge,
// vs 16 consumer-lane loads in R8). Consumers read pre-scaled ws from LDS.
// Product order identical -> bit-identical numerics.
__global__ __launch_bounds__(256) void k_agg_h2(const int2* __restrict__ offse,
                                                const int2* __restrict__ edata,
                                                const float* __restrict__ dinv,
                                                const _Float16* __restrict__ h,
                                                const float* __restrict__ b1,
                                                const float* __restrict__ W2,
                                                float* __restrict__ h2p, int N) {
    __shared__ int2 stage[4][68];      // 4 waves x (4 groups x 17 padded) = 2176 B
    int wv = threadIdx.x >> 6;
    int l  = threadIdx.x & 63;
    int g  = l >> 4;                   // node group within wave (0..3)
    unsigned fq = (unsigned)(l & 15);  // feature quad: features 4fq..4fq+3
    int sbase = g * 17;                // padded LDS base for this group
    int vv = blockIdx.x * 16 + wv * 4 + g;
    bool ok = vv < N;
    int v = ok ? vv : N - 1;           // clamp (harmless duplicate work)
    const hq4* hp = (const hq4*)h;     // hp[(src<<4)|fq] = 4 features (8B)

    float di = dinv[v];
    int2 oe = offse[v];

    // self-loop (norm di*1*di): src-side di applied here, col-side at the end
    hq4 sv4 = hp[((unsigned)v << 4) | fq];
    float a0 = di * (float)sv4.x, a1 = di * (float)sv4.y;
    float a2 = di * (float)sv4.z, a3 = di * (float)sv4.w;

    int deg = oe.y - oe.x;
    for (int base = 0; base < deg; base += 16) {   // divergent only across groups
        int idx = oe.x + base + (int)fq;
        int2 pr;
        pr.x = 0; pr.y = 0;            // dummy: src 0, ws = 0
        if (idx < oe.y) {
            pr = edata[idx];
            pr.y = __float_as_int(__int_as_float(pr.y) * dinv[pr.x]);  // ws once
        }
        stage[wv][sbase + (int)fq] = pr;   // wave-private row; no block barrier
#pragma unroll
        for (int k = 0; k < 16; ++k) {
            int2 em = stage[wv][sbase + k];   // 16-lane broadcast per group
            float ws = __int_as_float(em.y);  // pre-scaled w*dinv[src]
            hq4 hv = hp[((unsigned)em.x << 4) | fq];
            a0 += ws * (float)hv.x;
            a1 += ws * (float)hv.y;
            a2 += ws * (float)hv.z;
            a3 += ws * (float)hv.w;
        }
    }

    a0 = di * a0; a1 = di * a1; a2 = di * a2; a3 = di * a3;
    f4 bb = ((const f4*)b1)[fq];
    f4 ww = ((const f4*)W2)[fq];
    float s = fmaxf(a0 + bb.x, 0.f) * ww.x
            + fmaxf(a1 + bb.y, 0.f) * ww.y
            + fmaxf(a2 + bb.z, 0.f) * ww.z
            + fmaxf(a3 + bb.w, 0.f) * ww.w;
    // reduce over the 16 feature-quad lanes (tree rooted at lane 16g)
    s += __shfl_down(s, 8);
    s += __shfl_down(s, 4);
    s += __shfl_down(s, 2);
    s += __shfl_down(s, 1);
    if (fq == 0 && ok) h2p[vv] = di * s;   // store dinv-scaled hidden
}

// ---------- layer-2 aggregation: 16 lanes per node; h2p pre-scaled ----------
__global__ __launch_bounds__(256) void k_out(const int2* __restrict__ offse,
                                             const int2* __restrict__ edata,
                                             const float* __restrict__ dinv,
                                             const float* __restrict__ h2p,
                                             const float* __restrict__ b2,
                                             float* __restrict__ out, int N) {
    int t = blockIdx.x * 256 + threadIdx.x;
    int v = t >> 4;
    if (v >= N) return;
    int c = t & 15;
    int2 oe = offse[v];
    float s = 0.f;
    for (int i = oe.x + c; i < oe.y; i += 16) {
        int2 pr = edata[i];
        s += __int_as_float(pr.y) * h2p[(unsigned)pr.x];
    }
    s += __shfl_down(s, 8);
    s += __shfl_down(s, 4);
    s += __shfl_down(s, 2);
    s += __shfl_down(s, 1);
    if (c == 0) {
        float di = dinv[v];
        out[v] = b2[0] + di * (h2p[v] + s);   // h2p[v] = di*h2[v]
    }
}

extern "C" void kernel_launch(void* const* d_in, const int* in_sizes, int n_in,
                              void* d_out, int out_size, void* d_ws, size_t ws_size,
                              hipStream_t stream) {
    const float* x  = (const float*)d_in[0];
    const int*   ei = (const int*)d_in[1];
    const float* ew = (const float*)d_in[2];
    const float* W1 = (const float*)d_in[3];
    const float* b1 = (const float*)d_in[4];
    const float* W2 = (const float*)d_in[5];
    const float* b2 = (const float*)d_in[6];
    float* out = (float*)d_out;

    const int N = in_sizes[0] / DF;       // 100000
    const int E = in_sizes[2];            // 1600000
    const int* row = ei;                  // sources
    const int* col = ei + E;              // targets

    const int nbin = (N + 255) / 256;     // 391 coarse buckets
    const int nblk = (E + EPB - 1) / EPB; // 391 sort blocks

    // ---- workspace layout, ~46.5 MB ----
    size_t    gsz   = (size_t)nbin * CAP;                 // gapped entry count
    int2*     edata = (int2*)d_ws;                        // 16.0 MB
    int2*     tmp   = edata + gsz;                        // 16.0 MB
    _Float16* h     = (_Float16*)(tmp + gsz);             // N*64 fp16 = 12.8 MB
    int       nbinPad = (nbin + 3) & ~3;
    int*      cur   = (int*)(h + (size_t)N * 64);         // nbinPad ints
    float*    dinv  = (float*)(cur + nbinPad);            // N floats
    float*    h2p   = dinv + N;                           // N floats
    int2*     offse = (int2*)(h2p + N);                   // N int2

    const int B = 256;
    int nstrip = (N + 15) / 16;            // 6250 GEMM strips (16 nodes/wave)
    int gemmBlocks = (nstrip + 7) / 8;     // 8 waves per 512-thread block
    int gAgg = (N + 15) / 16;              // 16 nodes per block (4 nodes/wave)
    int gN16 = (N * 16 + B - 1) / B;

    hipMemsetAsync(cur, 0, (size_t)nbinPad * sizeof(int), stream);
    kFusedA<<<nblk + gemmBlocks, 512, 0, stream>>>(row, col, ew, cur, tmp,
                                                   x, W1, h, E, nblk, nstrip, N);
    kB<<<nbin, 512, 0, stream>>>(tmp, cur, edata, offse, dinv, N);
    k_agg_h2<<<gAgg, B, 0, stream>>>(offse, edata, dinv, h, b1, W2, h2p, N);
    k_out<<<gN16, B, 0, stream>>>(offse, edata, dinv, h2p, b2, out, N);
}